// Round 2
// baseline (70403.577 us; speedup 1.0000x reference)
//
#include <hip/hip_runtime.h>
#include <hip/hip_bf16.h>
#include <stdint.h>

// Problem constants (from reference): H=1024, IN=1024, L=8, T=2048, OUT=1024.
// Reference quirk: EVERY layer consumes raw x_t, and ONE (h,c) pair is carried
// through all L*T = 16384 serial cell steps. Output = c_final @ W_out^T + b_out.
#define TSEQ 2048
#define NLAY 8

// ---- bf16 helpers (round-to-nearest-even pack, bit-shift unpack) ----
static __device__ __forceinline__ uint32_t f2bf(float f) {
  uint32_t u = __float_as_uint(f);
  return (u + 0x7FFFu + ((u >> 16) & 1u)) >> 16;
}
static __device__ __forceinline__ float bflo(uint32_t w) { return __uint_as_float(w << 16); }
static __device__ __forceinline__ float bfhi(uint32_t w) { return __uint_as_float(w & 0xFFFF0000u); }

// =====================================================================
// Kernel B: xproj = x @ W_ih^T + b_ih + b_hh  for all (t, l) — parallel GEMM
//   M=2048 (t), N=32768 (n = l*4096 + gate*1024 + unit), K=1024.
//   Output stored bf16, permuted per-consumer-WG contiguous:
//     xp[wg][t][l][r],  wg = unit>>2, r = (unit&3)*4 + gate   (128 bf16 / (wg,t))
// =====================================================================
__global__ __launch_bounds__(256) void kxproj(const float* __restrict__ x,
                                              const float* __restrict__ Wih,
                                              const float* __restrict__ bih,
                                              const float* __restrict__ bhh,
                                              uint16_t* __restrict__ xp) {
  __shared__ float xs[64][65];   // [t][k] tile (+1 pad: bank-conflict-free)
  __shared__ float wsm[64][65];  // [n][k] tile
  const int tid = threadIdx.x;
  const int tb = blockIdx.x << 6;  // t base (grid.x = 32)
  const int nb = blockIdx.y << 6;  // n base (grid.y = 512)
  const int lr = tid >> 4;         // load row 0..15
  const int lc = (tid & 15) << 2;  // load col group
  const int ty = tid >> 4;         // compute: 16x16 threads, 4x4 outputs each
  const int tx = tid & 15;
  float acc[4][4] = {};
  for (int kk = 0; kk < 1024; kk += 64) {
    __syncthreads();  // protect prior iteration's LDS reads
#pragma unroll
    for (int r4 = 0; r4 < 4; ++r4) {
      const int row = lr + (r4 << 4);
      const float4 xv4 = *(const float4*)&x[(size_t)(tb + row) * 1024 + kk + lc];
      const float4 wv4 = *(const float4*)&Wih[(size_t)(nb + row) * 1024 + kk + lc];
      // scalar LDS stores (padded stride breaks 16B alignment for b128)
      xs[row][lc + 0] = xv4.x; xs[row][lc + 1] = xv4.y;
      xs[row][lc + 2] = xv4.z; xs[row][lc + 3] = xv4.w;
      wsm[row][lc + 0] = wv4.x; wsm[row][lc + 1] = wv4.y;
      wsm[row][lc + 2] = wv4.z; wsm[row][lc + 3] = wv4.w;
    }
    __syncthreads();
#pragma unroll 4
    for (int k = 0; k < 64; ++k) {
      float xv[4], wv[4];
#pragma unroll
      for (int i = 0; i < 4; ++i) xv[i] = xs[(ty << 2) + i][k];
#pragma unroll
      for (int j = 0; j < 4; ++j) wv[j] = wsm[(tx << 2) + j][k];
#pragma unroll
      for (int i = 0; i < 4; ++i)
#pragma unroll
        for (int j = 0; j < 4; ++j) acc[i][j] += xv[i] * wv[j];
    }
  }
#pragma unroll
  for (int i = 0; i < 4; ++i) {
    const int t = tb + (ty << 2) + i;
#pragma unroll
    for (int j = 0; j < 4; ++j) {
      const int n = nb + (tx << 2) + j;
      const float v = acc[i][j] + bih[n] + bhh[n];  // b_ih/b_hh flat [32768] share n-indexing
      const int l = n >> 12;
      const int g = (n >> 10) & 3;  // 0=i 1=f 2=g 3=o (PyTorch row order)
      const int u = n & 1023;
      xp[(size_t)(u >> 2) * (TSEQ * 128) + (size_t)t * 128 + l * 16 + ((u & 3) << 2) + g] =
          (uint16_t)f2bf(v);
    }
  }
}

// =====================================================================
// Dataflow h-exchange: hist is a 2-slot ring of 1024 (tag<<32 | f32bits) words.
// Step s (1..16384) reads tag s-1 from slot (s-1)&1, publishes tag s to slot s&1.
// Skew between WGs is provably <=1 step => 2 slots suffice; value+tag travel in
// ONE 8B agent-scope atomic, so no fences/barriers are needed.
// =====================================================================
static __device__ __forceinline__ void consume_h(unsigned long long* __restrict__ src,
                                                 unsigned want, float* __restrict__ hl,
                                                 int tid) {
  bool d0 = false, d1 = false, d2 = false, d3 = false;
  for (;;) {
    if (!d0) {
      unsigned long long v =
          __hip_atomic_load(&src[tid], __ATOMIC_RELAXED, __HIP_MEMORY_SCOPE_AGENT);
      if ((unsigned)(v >> 32) == want) { hl[tid] = __uint_as_float((unsigned)v); d0 = true; }
    }
    if (!d1) {
      unsigned long long v =
          __hip_atomic_load(&src[tid + 256], __ATOMIC_RELAXED, __HIP_MEMORY_SCOPE_AGENT);
      if ((unsigned)(v >> 32) == want) { hl[tid + 256] = __uint_as_float((unsigned)v); d1 = true; }
    }
    if (!d2) {
      unsigned long long v =
          __hip_atomic_load(&src[tid + 512], __ATOMIC_RELAXED, __HIP_MEMORY_SCOPE_AGENT);
      if ((unsigned)(v >> 32) == want) { hl[tid + 512] = __uint_as_float((unsigned)v); d2 = true; }
    }
    if (!d3) {
      unsigned long long v =
          __hip_atomic_load(&src[tid + 768], __ATOMIC_RELAXED, __HIP_MEMORY_SCOPE_AGENT);
      if ((unsigned)(v >> 32) == want) { hl[tid + 768] = __uint_as_float((unsigned)v); d3 = true; }
    }
    if (d0 && d1 && d2 && d3) return;
    __builtin_amdgcn_s_sleep(1);  // ~64 cyc backoff: don't hammer L3
  }
}

// =====================================================================
// Kernel C: persistent recurrence. 256 WGs x 256 thr (1 WG/CU, 1 wave/SIMD).
//   wave `w` of WG `wg` owns hidden unit u = wg*4+w (its 4 gate rows, all 8
//   layers) with W_hh held as packed bf16x2 in 256 statically-indexed VGPRs.
//   Per step: poll/stage h -> LDS, 64 FMA/lane dot, butterfly reduce,
//   pointwise LSTM (all lanes, redundantly), publish h via one 8B atomic.
// =====================================================================
__global__ __launch_bounds__(256, 1) void krnn(const float* __restrict__ Whh,
                                               const float* __restrict__ Wout,
                                               const float* __restrict__ bout,
                                               const uint16_t* __restrict__ xp,
                                               unsigned long long* __restrict__ hist,
                                               float* __restrict__ out) {
  const int tid = threadIdx.x;
  const int wg = blockIdx.x;
  const int wave = tid >> 6, lane = tid & 63;
  const int u = (wg << 2) + wave;  // this wave's hidden unit
  __shared__ float hl[1024];

  // ---- pack this wave's W_hh rows into registers: w2[l][g][m] holds
  //      (k = m*128+lane) | (k = m*128+64+lane)<<16, bf16 each. Fully static. ----
  uint32_t w2[8][4][8];
#pragma unroll
  for (int l = 0; l < 8; ++l)
#pragma unroll
    for (int g = 0; g < 4; ++g) {
      const float* wr = &Whh[(size_t)(l * 4096 + g * 1024 + u) * 1024];
#pragma unroll
      for (int m = 0; m < 8; ++m) {
        const float f0 = wr[m * 128 + lane];
        const float f1 = wr[m * 128 + 64 + lane];
        w2[l][g][m] = f2bf(f0) | (f2bf(f1) << 16);
      }
    }

  // ---- xproj stream: lanes 0..7 hold layer=lane's 4 bf16 (this wave's unit),
  //      register-double-buffered one timestep ahead. ----
  const size_t xpb = (size_t)wg * 4 * (TSEQ * 128) / 4;  // = wg * TSEQ*128
  unsigned xpx_cur = 0, xpy_cur = 0;
  if (lane < 8) {
    const uint2 v = *(const uint2*)&xp[xpb + 0 * 128 + lane * 16 + (wave << 2)];
    xpx_cur = v.x; xpy_cur = v.y;
  }

  float c = 0.f;  // cell state for unit u (maintained redundantly by all lanes)
  for (int t = 0; t < TSEQ; ++t) {
    unsigned xpx_nxt = xpx_cur, xpy_nxt = xpy_cur;
    if (lane < 8) {
      const int tn = (t + 1 < TSEQ) ? (t + 1) : t;
      const uint2 v = *(const uint2*)&xp[xpb + (size_t)tn * 128 + lane * 16 + (wave << 2)];
      xpx_nxt = v.x; xpy_nxt = v.y;
    }
#pragma unroll
    for (int l = 0; l < 8; ++l) {
      const unsigned want = (unsigned)(t * 8 + l);  // tag of h(step-1); slots are compile-time
      consume_h(&hist[(l & 1) * 1024], want, hl, tid);
      __syncthreads();  // hl fully staged

      float a0 = 0.f, a1 = 0.f, a2 = 0.f, a3 = 0.f;
#pragma unroll
      for (int m = 0; m < 8; ++m) {
        const float h0 = hl[m * 128 + lane];        // bank = lane%32: 2-way (free)
        const float h1 = hl[m * 128 + 64 + lane];
        const uint32_t q0 = w2[l][0][m], q1 = w2[l][1][m];
        const uint32_t q2 = w2[l][2][m], q3 = w2[l][3][m];
        a0 += bflo(q0) * h0 + bfhi(q0) * h1;
        a1 += bflo(q1) * h0 + bfhi(q1) * h1;
        a2 += bflo(q2) * h0 + bfhi(q2) * h1;
        a3 += bflo(q3) * h0 + bfhi(q3) * h1;
      }
#pragma unroll
      for (int off = 32; off > 0; off >>= 1) {  // butterfly: all lanes get full sums
        a0 += __shfl_xor(a0, off, 64);
        a1 += __shfl_xor(a1, off, 64);
        a2 += __shfl_xor(a2, off, 64);
        a3 += __shfl_xor(a3, off, 64);
      }
      const unsigned px = __shfl(xpx_cur, l, 64);  // layer l's xproj (4 bf16)
      const unsigned py = __shfl(xpy_cur, l, 64);
      const float pre_i = a0 + bflo(px);
      const float pre_f = a1 + bfhi(px);
      const float pre_g = a2 + bflo(py);
      const float pre_o = a3 + bfhi(py);
      const float ig = 1.f / (1.f + __expf(-pre_i));
      const float fg = 1.f / (1.f + __expf(-pre_f));
      const float gg = tanhf(pre_g);
      const float og = 1.f / (1.f + __expf(-pre_o));
      c = fg * c + ig * gg;
      const float hn = og * tanhf(c);
      if (lane == 0) {
        const unsigned long long pk =
            ((unsigned long long)(want + 1) << 32) | (unsigned long long)__float_as_uint(hn);
        __hip_atomic_store(&hist[((l + 1) & 1) * 1024 + u], pk, __ATOMIC_RELAXED,
                           __HIP_MEMORY_SCOPE_AGENT);
      }
      __syncthreads();  // hl reads done before next step's consume overwrites
    }
    xpx_cur = xpx_nxt; xpy_cur = xpy_nxt;
  }

  // ---- epilogue: publish c through the same ring (tag 16385). The dummy
  //      consume of h(16384) first guarantees every WG has finished step 16384,
  //      so overwriting slot 1 (old tag 16383) is safe. ----
  consume_h(&hist[0], (unsigned)(TSEQ * 8), hl, tid);  // slot 16384&1 = 0
  __syncthreads();
  if (lane == 0) {
    const unsigned long long pk =
        ((unsigned long long)(TSEQ * 8 + 1) << 32) | (unsigned long long)__float_as_uint(c);
    __hip_atomic_store(&hist[1024 + u], pk, __ATOMIC_RELAXED, __HIP_MEMORY_SCOPE_AGENT);
  }
  consume_h(&hist[1024], (unsigned)(TSEQ * 8 + 1), hl, tid);  // hl := c vector
  __syncthreads();

  // out[u] = c . W_out[u,:] + b_out[u]   (wave `wave` computes output row u)
  float s = 0.f;
  const float* wrow = &Wout[(size_t)u * 1024];
#pragma unroll
  for (int m = 0; m < 16; ++m) s += hl[m * 64 + lane] * wrow[m * 64 + lane];
#pragma unroll
  for (int off = 32; off > 0; off >>= 1) s += __shfl_xor(s, off, 64);
  if (lane == 0) out[u] = s + bout[u];
}

// =====================================================================
extern "C" void kernel_launch(void* const* d_in, const int* in_sizes, int n_in,
                              void* d_out, int out_size, void* d_ws, size_t ws_size,
                              hipStream_t stream) {
  (void)in_sizes; (void)n_in; (void)out_size;
  const float* x   = (const float*)d_in[0];
  const float* Wih = (const float*)d_in[1];
  const float* Whh = (const float*)d_in[2];
  const float* bih = (const float*)d_in[3];
  const float* bhh = (const float*)d_in[4];
  const float* Wou = (const float*)d_in[5];
  const float* bou = (const float*)d_in[6];
  float* out = (float*)d_out;

  const size_t XP_BYTES = (size_t)256 * TSEQ * 128 * sizeof(uint16_t);  // 128 MiB
  const size_t HIST_BYTES = 2048 * sizeof(unsigned long long);          // 16 KiB
  if (ws_size < XP_BYTES + HIST_BYTES) return;  // fail visibly (absmax), don't corrupt

  uint16_t* xp = (uint16_t*)d_ws;
  unsigned long long* hist = (unsigned long long*)((char*)d_ws + XP_BYTES);

  // slot0 tags=0 with h(0)=0.0f bits => plain zeros; ws is re-poisoned each call.
  hipMemsetAsync(hist, 0, HIST_BYTES, stream);
  kxproj<<<dim3(32, 512), 256, 0, stream>>>(x, Wih, bih, bhh, xp);

  void* args[] = {(void*)&Whh, (void*)&Wou, (void*)&bou, (void*)&xp, (void*)&hist, (void*)&out};
  if (hipLaunchCooperativeKernel((const void*)krnn, dim3(256), dim3(256), args, 0, stream) !=
      hipSuccess) {
    // 256 blocks x 256 thr on 256 CUs is trivially co-resident; normal launch fallback.
    krnn<<<256, 256, 0, stream>>>(Whh, Wou, bou, xp, hist, out);
  }
}